// Round 3
// baseline (542.684 us; speedup 1.0000x reference)
//
#include <hip/hip_runtime.h>

typedef __bf16 bf16_t;
typedef __bf16 bf16x4 __attribute__((ext_vector_type(4)));
typedef __bf16 bf16x8 __attribute__((ext_vector_type(8)));
typedef float f32x4 __attribute__((ext_vector_type(4)));

#define D_DIM 256
#define LOG2E 1.4426950408889634f
#define LN2   0.6931471805599453f
#define TILES 32            // 4096 cols per block / 128 cols per tile

#if __has_builtin(__builtin_amdgcn_exp2f)
static __device__ __forceinline__ float exp2_fast(float x) { return __builtin_amdgcn_exp2f(x); }
#else
static __device__ __forceinline__ float exp2_fast(float x) { return __expf(x * LN2); }
#endif
#if __has_builtin(__builtin_amdgcn_logf)
static __device__ __forceinline__ float log2_fast(float x) { return __builtin_amdgcn_logf(x); }
#else
static __device__ __forceinline__ float log2_fast(float x) { return __logf(x) * LOG2E; }
#endif

// Kernel 1: row L2-normalize img and txt (fp32 -> bf16), zero the output.
__global__ __launch_bounds__(256) void norm_cast_kernel(
    const float* __restrict__ img, const float* __restrict__ txt,
    bf16_t* __restrict__ Ab, bf16_t* __restrict__ Bb,
    float* __restrict__ out, int N)
{
    int wave = threadIdx.x >> 6;
    int lane = threadIdx.x & 63;
    int row  = blockIdx.x * 4 + wave;      // 0 .. 2N-1 (img rows then txt rows)

    const float* src;
    bf16_t* dst;
    if (row < N) {
        src = img + (size_t)row * D_DIM;
        dst = Ab  + (size_t)row * D_DIM;
    } else {
        src = txt + (size_t)(row - N) * D_DIM;
        dst = Bb  + (size_t)(row - N) * D_DIM;
    }

    float4 v = ((const float4*)src)[lane];
    float ss = v.x * v.x + v.y * v.y + v.z * v.z + v.w * v.w;
#pragma unroll
    for (int off = 32; off > 0; off >>= 1)
        ss += __shfl_xor(ss, off, 64);

    float inv = 1.0f / fmaxf(sqrtf(ss), 1e-12f);

    bf16x4 o;
    o[0] = (bf16_t)(v.x * inv);
    o[1] = (bf16_t)(v.y * inv);
    o[2] = (bf16_t)(v.z * inv);
    o[3] = (bf16_t)(v.w * inv);
    *(bf16x4*)(dst + lane * 4) = o;

    if (blockIdx.x == 0 && threadIdx.x == 0) out[0] = 0.0f;
}

// Kernel 2: persistent A-strip SigLIP loss.
// Block (512 thr, 8 waves) owns 128 img rows x 4096 txt cols.
//   - A strip (128x256 bf16, 64 KB) staged to LDS ONCE (one barrier total).
//   - 32 tiles of 128x128, NO barriers in the tile loop: B fragments are
//     loaded global->VGPR (L2-resident), double-buffered per k-step.
//   - A LDS layout: 8 k-slabs of [row][4 chunks of 8 bf16], with chunk index
//     XOR-swizzled by (row&3) to cut ds_read_b128 conflicts 8-way -> 4-way.
// Epilogue per tile in log2 domain, accumulated in a register; one atomic per block.
__global__ __launch_bounds__(512, 4) void siglip_loss_kernel(
    const bf16_t* __restrict__ A, const bf16_t* __restrict__ B,
    const float* __restrict__ t_prime, const float* __restrict__ bias,
    float* __restrict__ out, int N)
{
    __shared__ bf16_t As[8 * 128 * 32];   // 8 k-slabs x 128 rows x 32 elems = 64 KB
    __shared__ float red[8];

    const int tid  = threadIdx.x;
    const int wave = tid >> 6;        // 0..7
    const int lane = tid & 63;
    const int m16  = lane & 15;
    const int quad = lane >> 4;       // 0..3
    const int wm   = wave >> 2;       // 0..1 : 64-row half
    const int wn   = wave & 3;        // 0..3 : 32-col slice

    const int strip    = blockIdx.x >> 2;       // 0..127
    const int q        = blockIdx.x & 3;        // 0..3
    const int rowBase  = strip * 128;
    const int colQBase = q * 4096;

    // ---- Stage A strip: wave w stages k-slab w (k in [w*32, w*32+32)).
    // Instruction c writes rows c*16..c*16+15 of the slab (1 KB contiguous).
    // Lane l -> LDS row c*16 + (l>>2), chunk l&3; global chunk is XOR-swizzled
    // so LDS(row, c) = G(row, c ^ (row&3)).
    {
        const bf16_t* Ag = A + (size_t)rowBase * D_DIM;
        const int ld_r = lane >> 2;
        const int ld_c = ((lane & 3) ^ (ld_r & 3)) * 8;   // swizzled source chunk
#pragma unroll
        for (int c = 0; c < 8; ++c) {
            const bf16_t* gp = Ag + (size_t)(c * 16 + ld_r) * D_DIM + wave * 32 + ld_c;
            __builtin_amdgcn_global_load_lds(
                (const __attribute__((address_space(1))) unsigned int*)gp,
                (__attribute__((address_space(3))) unsigned int*)&As[(wave * 128 + c * 16) * 32],
                16, 0, 0);
        }
    }
    __syncthreads();   // the ONLY barrier before the reduction

    const float s2 = __expf(t_prime[0]) * LOG2E;
    const float b2 = bias[0] * LOG2E;
    float local = 0.0f;

    // A fragment LDS addresses (elements), one per i-tile; row&3 == m16&3.
    int a_off[4];
#pragma unroll
    for (int i = 0; i < 4; ++i)
        a_off[i] = (wm * 64 + i * 16 + m16) * 32 + ((quad ^ (m16 & 3)) * 8);

    // B: wave's column slice base; lane reads row (col) c0+nt*16+m16, 8 bf16 at quad*8.
    const bf16_t* Bw = B + (size_t)(colQBase + wn * 32 + m16) * D_DIM + quad * 8;

#pragma unroll 1
    for (int t = 0; t < TILES; ++t) {
        const bf16_t* Bt = Bw + (size_t)t * 128 * D_DIM;

        f32x4 acc[4][2] = {};

        bf16x8 bc0 = *(const bf16x8*)(Bt);
        bf16x8 bc1 = *(const bf16x8*)(Bt + 16 * D_DIM);
#pragma unroll
        for (int k = 0; k < 8; ++k) {
            bf16x8 bn0, bn1;
            if (k < 7) {
                bn0 = *(const bf16x8*)(Bt + (k + 1) * 32);
                bn1 = *(const bf16x8*)(Bt + 16 * D_DIM + (k + 1) * 32);
            }
            bf16x8 av[4];
#pragma unroll
            for (int i = 0; i < 4; ++i)
                av[i] = *(const bf16x8*)&As[k * 128 * 32 + a_off[i]];
#pragma unroll
            for (int i = 0; i < 4; ++i) {
                acc[i][0] = __builtin_amdgcn_mfma_f32_16x16x32_bf16(av[i], bc0, acc[i][0], 0, 0, 0);
                acc[i][1] = __builtin_amdgcn_mfma_f32_16x16x32_bf16(av[i], bc1, acc[i][1], 0, 0, 0);
            }
            bc0 = bn0; bc1 = bn1;
        }

        // ---- Epilogue for this tile (log2-domain softplus).
        const int colTile = colQBase + t * 128;
        if (rowBase != colTile) {
#pragma unroll
            for (int i = 0; i < 4; ++i)
#pragma unroll
                for (int j = 0; j < 2; ++j)
#pragma unroll
                    for (int r = 0; r < 4; ++r) {
                        float z2 = fmaf(s2, acc[i][j][r], b2);
                        local += log2_fast(1.0f + exp2_fast(z2));
                    }
        } else {
#pragma unroll
            for (int i = 0; i < 4; ++i)
#pragma unroll
                for (int j = 0; j < 2; ++j)
#pragma unroll
                    for (int r = 0; r < 4; ++r) {
                        // C/D layout: col = lane&15, row = quad*4 + r (m89/m91)
                        float z2 = fmaf(s2, acc[i][j][r], b2);
                        local += log2_fast(1.0f + exp2_fast(z2));
                        int grow = wm * 64 + i * 16 + quad * 4 + r;
                        int gcol = wn * 32 + j * 16 + m16;
                        if (grow == gcol) local -= z2;   // softplus(-z) = softplus(z) - z
                    }
        }
    }

#pragma unroll
    for (int off = 32; off > 0; off >>= 1)
        local += __shfl_xor(local, off, 64);
    if (lane == 0) red[wave] = local;
    __syncthreads();
    if (tid == 0) {
        float total = 0.0f;
#pragma unroll
        for (int w = 0; w < 8; ++w) total += red[w];
        atomicAdd(out, total * (LN2 / (float)N));
    }
}

extern "C" void kernel_launch(void* const* d_in, const int* in_sizes, int n_in,
                              void* d_out, int out_size, void* d_ws, size_t ws_size,
                              hipStream_t stream) {
    const float* img = (const float*)d_in[0];
    const float* txt = (const float*)d_in[1];
    const float* tp  = (const float*)d_in[2];
    const float* bs  = (const float*)d_in[3];
    float* out = (float*)d_out;
    int N = in_sizes[0] / D_DIM;    // 16384

    bf16_t* Ab = (bf16_t*)d_ws;                 // N*256 bf16 = 8 MB
    bf16_t* Bb = Ab + (size_t)N * D_DIM;        // +8 MB (ws >= 16 MB)

    norm_cast_kernel<<<(2 * N) / 4, 256, 0, stream>>>(img, txt, Ab, Bb, out, N);

    // 128 row-strips x 4 column-quarters = 512 blocks (2 per CU).
    siglip_loss_kernel<<<512, 512, 0, stream>>>(Ab, Bb, tp, bs, out, N);
}

// Round 4
// 306.785 us; speedup vs baseline: 1.7689x; 1.7689x over previous
//
#include <hip/hip_runtime.h>

typedef __bf16 bf16_t;
typedef __bf16 bf16x4 __attribute__((ext_vector_type(4)));
typedef __bf16 bf16x8 __attribute__((ext_vector_type(8)));
typedef float f32x4 __attribute__((ext_vector_type(4)));

#define D_DIM 256
#define LOG2E 1.4426950408889634f
#define LN2   0.6931471805599453f

#if __has_builtin(__builtin_amdgcn_exp2f)
static __device__ __forceinline__ float exp2_fast(float x) { return __builtin_amdgcn_exp2f(x); }
#else
static __device__ __forceinline__ float exp2_fast(float x) { return __expf(x * LN2); }
#endif
#if __has_builtin(__builtin_amdgcn_logf)
static __device__ __forceinline__ float log2_fast(float x) { return __builtin_amdgcn_logf(x); }
#else
static __device__ __forceinline__ float log2_fast(float x) { return __logf(x) * LOG2E; }
#endif

// Kernel 1: row L2-normalize img and txt (fp32 -> bf16), zero the output.
__global__ __launch_bounds__(256) void norm_cast_kernel(
    const float* __restrict__ img, const float* __restrict__ txt,
    bf16_t* __restrict__ Ab, bf16_t* __restrict__ Bb,
    float* __restrict__ out, int N)
{
    int wave = threadIdx.x >> 6;
    int lane = threadIdx.x & 63;
    int row  = blockIdx.x * 4 + wave;      // 0 .. 2N-1 (img rows then txt rows)

    const float* src;
    bf16_t* dst;
    if (row < N) {
        src = img + (size_t)row * D_DIM;
        dst = Ab  + (size_t)row * D_DIM;
    } else {
        src = txt + (size_t)(row - N) * D_DIM;
        dst = Bb  + (size_t)(row - N) * D_DIM;
    }

    float4 v = ((const float4*)src)[lane];
    float ss = v.x * v.x + v.y * v.y + v.z * v.z + v.w * v.w;
#pragma unroll
    for (int off = 32; off > 0; off >>= 1)
        ss += __shfl_xor(ss, off, 64);

    float inv = 1.0f / fmaxf(sqrtf(ss), 1e-12f);

    bf16x4 o;
    o[0] = (bf16_t)(v.x * inv);
    o[1] = (bf16_t)(v.y * inv);
    o[2] = (bf16_t)(v.z * inv);
    o[3] = (bf16_t)(v.w * inv);
    *(bf16x4*)(dst + lane * 4) = o;

    if (blockIdx.x == 0 && threadIdx.x == 0) out[0] = 0.0f;
}

// Kernel 2: fused sum(softplus(scale*A@B^T + bias)) - diag, 128x128 tile,
// 4 waves x (4x4 of 16x16x32 bf16 MFMA). R4 changes vs R2:
//  - double-buffered LDS, ONE barrier per K-iter, prefetch issued right after
//    the barrier so the vmcnt(0)-before-barrier only drains loads that had a
//    full compute phase in flight.
//  - XOR swizzle chunk ^= (row>>1)&3 on the 16B chunks: staging stays 64B
//    coalesced, ds_read_b128 drops from 4-8-way to 2-way (free) conflicts.
__global__ __launch_bounds__(256, 4) void siglip_loss_kernel(
    const bf16_t* __restrict__ A, const bf16_t* __restrict__ B,
    const float* __restrict__ t_prime, const float* __restrict__ bias,
    float* __restrict__ out, int N)
{
    __shared__ bf16_t As[2][128 * 32];   // 2 x 8 KB
    __shared__ bf16_t Bs[2][128 * 32];
    __shared__ float red[4];

    const int tid   = threadIdx.x;
    const int wave  = tid >> 6;
    const int lane  = tid & 63;
    const int m16   = lane & 15;
    const int quad  = lane >> 4;      // 0..3
    const int wm    = wave >> 1;      // 0..1
    const int wn    = wave & 1;       // 0..1

    const int rowBase = blockIdx.y * 128;
    const int colBase = blockIdx.x * 128;

    const bf16_t* Ag = A + (size_t)rowBase * D_DIM;
    const bf16_t* Bg = B + (size_t)colBase * D_DIM;

    // Staging map: lane l -> LDS row l>>2 (within 16-row chunk), 16B chunk l&3.
    // Source chunk XOR-swizzled by (row>>1)&3 so LDS(r,c) = G(r, c ^ ((r>>1)&3)).
    const int ld_r = lane >> 2;
    const int ld_c = ((lane & 3) ^ ((ld_r >> 1) & 3)) * 8;   // element offset

    f32x4 acc[4][4] = {};

    // Fragment LDS element offsets (row ~ m16 mod 16 in every tile).
    const int swz = (quad ^ ((m16 >> 1) & 3)) * 8;
    int a_off[4], b_off[4];
#pragma unroll
    for (int i = 0; i < 4; ++i) {
        a_off[i] = (wm * 64 + i * 16 + m16) * 32 + swz;
        b_off[i] = (wn * 64 + i * 16 + m16) * 32 + swz;
    }

    // stage K-chunk k0 into buffer `buf`
    auto stage = [&](int buf, int k0) {
#pragma unroll
        for (int l = 0; l < 2; ++l) {
            int r0 = wave * 16 + l * 64;   // wave-uniform chunk base row
            const bf16_t* gpA = Ag + (size_t)(r0 + ld_r) * D_DIM + k0 + ld_c;
            const bf16_t* gpB = Bg + (size_t)(r0 + ld_r) * D_DIM + k0 + ld_c;
            __builtin_amdgcn_global_load_lds(
                (const __attribute__((address_space(1))) unsigned int*)gpA,
                (__attribute__((address_space(3))) unsigned int*)&As[buf][r0 * 32],
                16, 0, 0);
            __builtin_amdgcn_global_load_lds(
                (const __attribute__((address_space(1))) unsigned int*)gpB,
                (__attribute__((address_space(3))) unsigned int*)&Bs[buf][r0 * 32],
                16, 0, 0);
        }
    };

    stage(0, 0);

#pragma unroll
    for (int t = 0; t < 8; ++t) {
        __syncthreads();               // publishes buffer t&1 (drains stage t)
        if (t < 7) stage((t + 1) & 1, (t + 1) * 32);   // prefetch in flight

        const bf16_t* as = As[t & 1];
        const bf16_t* bs = Bs[t & 1];
        bf16x8 av[4], bv[4];
#pragma unroll
        for (int i = 0; i < 4; ++i) {
            av[i] = *(const bf16x8*)&as[a_off[i]];
            bv[i] = *(const bf16x8*)&bs[b_off[i]];
        }
#pragma unroll
        for (int i = 0; i < 4; ++i)
#pragma unroll
            for (int j = 0; j < 4; ++j)
                acc[i][j] = __builtin_amdgcn_mfma_f32_16x16x32_bf16(
                    av[i], bv[j], acc[i][j], 0, 0, 0);
        // no trailing barrier: next iteration's barrier protects buffer reuse
        // (stage t+2 into buf t&1 only issues after ALL waves passed barrier
        //  t+1, i.e. after their ds_reads of buf t&1 completed).
    }

    // Epilogue in log2 domain: softplus(z)/ln2 = log2(1 + 2^(z*log2e)).
    const float s2 = __expf(t_prime[0]) * LOG2E;
    const float b2 = bias[0] * LOG2E;
    float local = 0.0f;

    if (rowBase != colBase) {
#pragma unroll
        for (int i = 0; i < 4; ++i)
#pragma unroll
            for (int j = 0; j < 4; ++j)
#pragma unroll
                for (int r = 0; r < 4; ++r) {
                    float z2 = fmaf(s2, acc[i][j][r], b2);
                    local += log2_fast(1.0f + exp2_fast(z2));
                }
    } else {
#pragma unroll
        for (int i = 0; i < 4; ++i)
#pragma unroll
            for (int j = 0; j < 4; ++j)
#pragma unroll
                for (int r = 0; r < 4; ++r) {
                    // C/D layout (m89/m91): col = lane&15, row = quad*4 + r
                    float z2 = fmaf(s2, acc[i][j][r], b2);
                    local += log2_fast(1.0f + exp2_fast(z2));
                    int grow = wm * 64 + i * 16 + quad * 4 + r;
                    int gcol = wn * 64 + j * 16 + m16;
                    if (grow == gcol) local -= z2;   // softplus(-z)=softplus(z)-z
                }
    }

#pragma unroll
    for (int off = 32; off > 0; off >>= 1)
        local += __shfl_xor(local, off, 64);
    if (lane == 0) red[wave] = local;
    __syncthreads();
    if (tid == 0) {
        float total = (red[0] + red[1]) + (red[2] + red[3]);
        atomicAdd(out, total * (LN2 / (float)N));
    }
}

extern "C" void kernel_launch(void* const* d_in, const int* in_sizes, int n_in,
                              void* d_out, int out_size, void* d_ws, size_t ws_size,
                              hipStream_t stream) {
    const float* img = (const float*)d_in[0];
    const float* txt = (const float*)d_in[1];
    const float* tp  = (const float*)d_in[2];
    const float* bs  = (const float*)d_in[3];
    float* out = (float*)d_out;
    int N = in_sizes[0] / D_DIM;    // 16384

    bf16_t* Ab = (bf16_t*)d_ws;                 // N*256 bf16 = 8 MB
    bf16_t* Bb = Ab + (size_t)N * D_DIM;        // +8 MB (ws >= 16 MB)

    norm_cast_kernel<<<(2 * N) / 4, 256, 0, stream>>>(img, txt, Ab, Bb, out, N);

    dim3 grid(N / 128, N / 128);
    siglip_loss_kernel<<<grid, 256, 0, stream>>>(Ab, Bb, tp, bs, out, N);
}

// Round 5
// 277.064 us; speedup vs baseline: 1.9587x; 1.1073x over previous
//
#include <hip/hip_runtime.h>

typedef __bf16 bf16_t;
typedef __bf16 bf16x4 __attribute__((ext_vector_type(4)));
typedef __bf16 bf16x8 __attribute__((ext_vector_type(8)));
typedef float f32x4 __attribute__((ext_vector_type(4)));

#define D_DIM 256
#define LOG2E 1.4426950408889634f
#define LN2   0.6931471805599453f
#define T_TILES 8    // 128-col tiles per block

#if __has_builtin(__builtin_amdgcn_exp2f)
static __device__ __forceinline__ float exp2_fast(float x) { return __builtin_amdgcn_exp2f(x); }
#else
static __device__ __forceinline__ float exp2_fast(float x) { return __expf(x * LN2); }
#endif
#if __has_builtin(__builtin_amdgcn_logf)
static __device__ __forceinline__ float log2_fast(float x) { return __builtin_amdgcn_logf(x); }
#else
static __device__ __forceinline__ float log2_fast(float x) { return __logf(x) * LOG2E; }
#endif

// Kernel 1: L2-normalize rows fp32->bf16. img rows are additionally scaled by
// s2 = exp(t')*log2e, so the GEMM accumulator directly yields z2 = z*log2e - b2.
// Also zeroes out[0] (poisoned before every call).
__global__ __launch_bounds__(256) void norm_cast_kernel(
    const float* __restrict__ img, const float* __restrict__ txt,
    const float* __restrict__ t_prime,
    bf16_t* __restrict__ Ab, bf16_t* __restrict__ Bb,
    float* __restrict__ out, int N)
{
    int wave = threadIdx.x >> 6;
    int lane = threadIdx.x & 63;
    int row  = blockIdx.x * 4 + wave;      // 0 .. 2N-1

    const float* src;
    bf16_t* dst;
    float scale;
    if (row < N) {
        src = img + (size_t)row * D_DIM;
        dst = Ab  + (size_t)row * D_DIM;
        scale = __expf(t_prime[0]) * LOG2E;    // fold s2 into A
    } else {
        src = txt + (size_t)(row - N) * D_DIM;
        dst = Bb  + (size_t)(row - N) * D_DIM;
        scale = 1.0f;
    }

    float4 v = ((const float4*)src)[lane];
    float ss = v.x * v.x + v.y * v.y + v.z * v.z + v.w * v.w;
#pragma unroll
    for (int off = 32; off > 0; off >>= 1)
        ss += __shfl_xor(ss, off, 64);

    float inv = scale / fmaxf(sqrtf(ss), 1e-12f);

    bf16x4 o;
    o[0] = (bf16_t)(v.x * inv);
    o[1] = (bf16_t)(v.y * inv);
    o[2] = (bf16_t)(v.z * inv);
    o[3] = (bf16_t)(v.w * inv);
    *(bf16x4*)(dst + lane * 4) = o;

    if (blockIdx.x == 0 && threadIdx.x == 0) out[0] = 0.0f;
}

// Kernel 2: diagonal correction. loss*N/ln2 needs -sum_i z2_ii; z2_ii =
// dot(A'_i,B_i) + b2 (s2 already folded into A'). Sum of partials is linear,
// so each lane accumulates its partial dots; N*b2 term collapses to -bias.
__global__ __launch_bounds__(256) void diag_kernel(
    const bf16_t* __restrict__ A, const bf16_t* __restrict__ B,
    const float* __restrict__ bias, float* __restrict__ out, int N)
{
    int gw   = (blockIdx.x * 256 + threadIdx.x) >> 6;   // 512 waves
    int lane = threadIdx.x & 63;
    float sum = 0.0f;
#pragma unroll 4
    for (int r = 0; r < 32; ++r) {
        int row = gw * 32 + r;
        bf16x4 a = *(const bf16x4*)&A[(size_t)row * D_DIM + lane * 4];
        bf16x4 b = *(const bf16x4*)&B[(size_t)row * D_DIM + lane * 4];
        sum += (float)a[0] * (float)b[0] + (float)a[1] * (float)b[1]
             + (float)a[2] * (float)b[2] + (float)a[3] * (float)b[3];
    }
#pragma unroll
    for (int off = 32; off > 0; off >>= 1)
        sum += __shfl_xor(sum, off, 64);
    if (lane == 0) atomicAdd(out, -sum * (LN2 / (float)N));
    if (blockIdx.x == 0 && threadIdx.x == 0)
        atomicAdd(out, -bias[0]);   // -(LN2/N) * N * b2 == -bias
}

// Kernel 3: main GEMM+softplus. Block = 128 rows x T_TILES*128 cols.
//  - A strip (128x256, 64 KB) persistent in LDS, staged once.
//  - B tiles staged per 32-K chunk, double-buffered (2x8 KB), 1 barrier/iter.
//  - Epilogue of tile t-1 (pure register VALU) interleaved into tile t's
//    K-loop -> executes in the barrier/vmcnt stall shadow.
//  - Epilogue math: sum log2(1+2^z2) via product-of-8: p = fma(p,x,p).
//  - 16B-chunk XOR swizzle (row>>1)&3 on both LDS arrays: 0 bank conflicts (R4).
__global__ __launch_bounds__(256, 2) void siglip_loss_kernel(
    const bf16_t* __restrict__ A, const bf16_t* __restrict__ B,
    const float* __restrict__ bias, float* __restrict__ out, int N)
{
    __shared__ bf16_t As[8 * 128 * 32];   // 64 KB, [k-chunk][row][32]
    __shared__ bf16_t Bs[2][128 * 32];    // 16 KB  (total 81920 = 2 blocks/CU)

    const int tid  = threadIdx.x;
    const int wave = tid >> 6;
    const int lane = tid & 63;
    const int m16  = lane & 15;
    const int quad = lane >> 4;
    const int wm   = wave >> 1;       // 2x2 wave grid over 128x128
    const int wn   = wave & 1;

    const int rowBase = blockIdx.x * 128;             // 128 strips
    const int colBase = blockIdx.y * (T_TILES * 128); // 16 col groups

    const bf16_t* Ag = A + (size_t)rowBase * D_DIM;
    const bf16_t* Bg = B + (size_t)colBase * D_DIM;

    // staging lane map (R4-verified): row = l>>2, 16B chunk (l&3)^((row>>1)&3)
    const int ld_r = lane >> 2;
    const int ld_c = ((lane & 3) ^ ((ld_r >> 1) & 3)) * 8;

    // fragment read offsets (row%16 == m16)
    const int swz = (quad ^ ((m16 >> 1) & 3)) * 8;
    int a_off[4], b_off[4];
#pragma unroll
    for (int i = 0; i < 4; ++i) {
        a_off[i] = (wm * 64 + i * 16 + m16) * 32 + swz;
        b_off[i] = (wn * 64 + i * 16 + m16) * 32 + swz;
    }

    // ---- stage all of A (8 chunks x 128 rows), 16 instrs/wave
#pragma unroll
    for (int kk = 0; kk < 8; ++kk)
#pragma unroll
        for (int l = 0; l < 2; ++l) {
            int r0 = wave * 16 + l * 64;
            const bf16_t* gp = Ag + (size_t)(r0 + ld_r) * D_DIM + kk * 32 + ld_c;
            __builtin_amdgcn_global_load_lds(
                (const __attribute__((address_space(1))) unsigned int*)gp,
                (__attribute__((address_space(3))) unsigned int*)&As[kk * 4096 + r0 * 32],
                16, 0, 0);
        }

    auto stageB = [&](int buf, int t, int kk) {
        const bf16_t* base = Bg + (size_t)(t * 128) * D_DIM + kk * 32;
#pragma unroll
        for (int l = 0; l < 2; ++l) {
            int r0 = wave * 16 + l * 64;
            const bf16_t* gp = base + (size_t)(r0 + ld_r) * D_DIM + ld_c;
            __builtin_amdgcn_global_load_lds(
                (const __attribute__((address_space(1))) unsigned int*)gp,
                (__attribute__((address_space(3))) unsigned int*)&Bs[buf][r0 * 32],
                16, 0, 0);
        }
    };

    stageB(0, 0, 0);

    const float b2 = bias[0] * LOG2E;
    float local = 0.0f;

    // epilogue slice: 8 elements of accP -> one log2 of a product of 8
    auto slice = [&](const f32x4 (&accP)[4][4], int i, int j0) {
        float x[8];
#pragma unroll
        for (int j = 0; j < 2; ++j)
#pragma unroll
            for (int r = 0; r < 4; ++r)
                x[j * 4 + r] = exp2_fast(accP[i][j0 + j][r] + b2);
        float p = 1.0f + x[0];
#pragma unroll
        for (int e = 1; e < 8; ++e)
            p = fmaf(p, x[e], p);    // p *= (1 + x[e])
        local += log2_fast(p);
    };

    f32x4 acc0[4][4], acc1[4][4];

    auto body = [&](f32x4 (&accC)[4][4], f32x4 (&accP)[4][4],
                    int t, bool doEpi, bool lastTile) {
#pragma unroll
        for (int k = 0; k < 8; ++k) {
            __syncthreads();           // publishes Bs[k&1] (and As on iter 0)
            if (k < 7)          stageB((k + 1) & 1, t, k + 1);
            else if (!lastTile) stageB(0, t + 1, 0);

            const bf16_t* bs = Bs[k & 1];
            bf16x8 av[4], bv[4];
#pragma unroll
            for (int i = 0; i < 4; ++i) {
                av[i] = *(const bf16x8*)&As[k * 4096 + a_off[i]];
                bv[i] = *(const bf16x8*)&bs[b_off[i]];
            }
#pragma unroll
            for (int i = 0; i < 4; ++i)
#pragma unroll
                for (int j = 0; j < 4; ++j) {
                    f32x4 c = (k == 0) ? f32x4{0.f, 0.f, 0.f, 0.f} : accC[i][j];
                    accC[i][j] = __builtin_amdgcn_mfma_f32_16x16x32_bf16(
                        av[i], bv[j], c, 0, 0, 0);
                }
            if (doEpi) slice(accP, k >> 1, (k & 1) * 2);   // fills stall shadow
        }
    };

#pragma unroll 1
    for (int tp = 0; tp < T_TILES / 2; ++tp) {
        body(acc0, acc1, 2 * tp,     tp > 0, false);
        body(acc1, acc0, 2 * tp + 1, true,   tp == T_TILES / 2 - 1);
    }
    // drain: epilogue of last tile (in acc1)
#pragma unroll
    for (int k = 0; k < 8; ++k)
        slice(acc1, k >> 1, (k & 1) * 2);

#pragma unroll
    for (int off = 32; off > 0; off >>= 1)
        local += __shfl_xor(local, off, 64);
    if (lane == 0)
        atomicAdd(out, local * (LN2 / (float)N));
}

extern "C" void kernel_launch(void* const* d_in, const int* in_sizes, int n_in,
                              void* d_out, int out_size, void* d_ws, size_t ws_size,
                              hipStream_t stream) {
    const float* img = (const float*)d_in[0];
    const float* txt = (const float*)d_in[1];
    const float* tp  = (const float*)d_in[2];
    const float* bs  = (const float*)d_in[3];
    float* out = (float*)d_out;
    int N = in_sizes[0] / D_DIM;    // 16384

    bf16_t* Ab = (bf16_t*)d_ws;                 // N*256 bf16 = 8 MB
    bf16_t* Bb = Ab + (size_t)N * D_DIM;        // +8 MB

    norm_cast_kernel<<<(2 * N) / 4, 256, 0, stream>>>(img, txt, tp, Ab, Bb, out, N);
    diag_kernel<<<128, 256, 0, stream>>>(Ab, Bb, bs, out, N);

    dim3 grid(N / 128, N / (T_TILES * 128));    // 128 x 16
    siglip_loss_kernel<<<grid, 256, 0, stream>>>(Ab, Bb, bs, out, N);
}

// Round 6
// 264.321 us; speedup vs baseline: 2.0531x; 1.0482x over previous
//
#include <hip/hip_runtime.h>

typedef __bf16 bf16_t;
typedef __bf16 bf16x4 __attribute__((ext_vector_type(4)));
typedef __bf16 bf16x8 __attribute__((ext_vector_type(8)));
typedef float f32x4 __attribute__((ext_vector_type(4)));
typedef float f32x16 __attribute__((ext_vector_type(16)));

#define D_DIM 256
#define LOG2E 1.4426950408889634f
#define LN2   0.6931471805599453f

#if __has_builtin(__builtin_amdgcn_exp2f)
static __device__ __forceinline__ float exp2_fast(float x) { return __builtin_amdgcn_exp2f(x); }
#else
static __device__ __forceinline__ float exp2_fast(float x) { return __expf(x * LN2); }
#endif
#if __has_builtin(__builtin_amdgcn_logf)
static __device__ __forceinline__ float log2_fast(float x) { return __builtin_amdgcn_logf(x); }
#else
static __device__ __forceinline__ float log2_fast(float x) { return __logf(x) * LOG2E; }
#endif

// Kernel 1: L2-normalize rows fp32->bf16; img rows pre-scaled by exp(t')*log2e
// so the GEMM accumulator is already z2 - b2 (log2 domain). Zeroes out[0].
__global__ __launch_bounds__(256) void norm_cast_kernel(
    const float* __restrict__ img, const float* __restrict__ txt,
    const float* __restrict__ t_prime,
    bf16_t* __restrict__ Ab, bf16_t* __restrict__ Bb,
    float* __restrict__ out, int N)
{
    int wave = threadIdx.x >> 6;
    int lane = threadIdx.x & 63;
    int row  = blockIdx.x * 4 + wave;

    const float* src;
    bf16_t* dst;
    float scale;
    if (row < N) {
        src = img + (size_t)row * D_DIM;
        dst = Ab  + (size_t)row * D_DIM;
        scale = __expf(t_prime[0]) * LOG2E;
    } else {
        src = txt + (size_t)(row - N) * D_DIM;
        dst = Bb  + (size_t)(row - N) * D_DIM;
        scale = 1.0f;
    }

    float4 v = ((const float4*)src)[lane];
    float ss = v.x * v.x + v.y * v.y + v.z * v.z + v.w * v.w;
#pragma unroll
    for (int off = 32; off > 0; off >>= 1)
        ss += __shfl_xor(ss, off, 64);

    float inv = scale / fmaxf(sqrtf(ss), 1e-12f);

    bf16x4 o;
    o[0] = (bf16_t)(v.x * inv);
    o[1] = (bf16_t)(v.y * inv);
    o[2] = (bf16_t)(v.z * inv);
    o[3] = (bf16_t)(v.w * inv);
    *(bf16x4*)(dst + lane * 4) = o;

    if (blockIdx.x == 0 && threadIdx.x == 0) out[0] = 0.0f;
}

// Kernel 2: diagonal correction (-sum_i z2_ii * ln2/N; N*b2 term == -bias).
__global__ __launch_bounds__(256) void diag_kernel(
    const bf16_t* __restrict__ A, const bf16_t* __restrict__ B,
    const float* __restrict__ bias, float* __restrict__ out, int N)
{
    int gw   = (blockIdx.x * 256 + threadIdx.x) >> 6;
    int lane = threadIdx.x & 63;
    float sum = 0.0f;
#pragma unroll 4
    for (int r = 0; r < 32; ++r) {
        int row = gw * 32 + r;
        bf16x4 a = *(const bf16x4*)&A[(size_t)row * D_DIM + lane * 4];
        bf16x4 b = *(const bf16x4*)&B[(size_t)row * D_DIM + lane * 4];
        sum += (float)a[0] * (float)b[0] + (float)a[1] * (float)b[1]
             + (float)a[2] * (float)b[2] + (float)a[3] * (float)b[3];
    }
#pragma unroll
    for (int off = 32; off > 0; off >>= 1)
        sum += __shfl_xor(sum, off, 64);
    if (lane == 0) atomicAdd(out, -sum * (LN2 / (float)N));
    if (blockIdx.x == 0 && threadIdx.x == 0)
        atomicAdd(out, -bias[0]);
}

// Kernel 3: main GEMM+softplus.
//  Block = 256x128 output, 4 waves in 2x2; wave tile = 128x64 as 4x2 of
//  32x32x16 bf16 MFMA (acc = 8 x f32x16 = 128 AGPR). K = 8 chunks of 32,
//  double-buffered LDS (A 2x16KB + B 2x8KB = 48 KB), ONE barrier per chunk
//  (8 per block), prefetch issued immediately after each barrier.
//  LDS 16B-chunk XOR swizzle p = c ^ ((row>>1)&3): staging stays coalesced,
//  and the 32-row fragment reads hit 8 distinct bank-groups per 8-lane
//  service group -> 0 conflicts (verified 0 in R4/R5 for same geometry).
__global__ __launch_bounds__(256, 2) void siglip_loss_kernel(
    const bf16_t* __restrict__ A, const bf16_t* __restrict__ B,
    const float* __restrict__ bias, float* __restrict__ out, int N)
{
    __shared__ bf16_t As[2][256 * 32];   // 2 x 16 KB
    __shared__ bf16_t Bs[2][128 * 32];   // 2 x 8 KB
    __shared__ float red[4];

    const int tid  = threadIdx.x;
    const int wave = tid >> 6;
    const int lane = tid & 63;
    const int r31  = lane & 31;
    const int half = lane >> 5;       // 0..1
    const int wv   = wave >> 1;       // row half (128 rows each)
    const int wu   = wave & 1;        // col half (64 cols each)

    const int rowBase = blockIdx.y * 256;
    const int colBase = blockIdx.x * 128;

    const bf16_t* Ag = A + (size_t)rowBase * D_DIM;
    const bf16_t* Bg = B + (size_t)colBase * D_DIM;

    // staging lane map (R4-verified): row = l>>2, src chunk (l&3)^((row>>1)&3)
    const int ld_r = lane >> 2;
    const int ld_c = ((lane & 3) ^ ((ld_r >> 1) & 3)) * 8;

    // fragment read: row r -> element addr r*32 + (chunk ^ ((r&31)>>1 & 3))*8
    const int pxor = (r31 >> 1) & 3;
    int a_row[4], b_row[2];
#pragma unroll
    for (int i = 0; i < 4; ++i) a_row[i] = (wv * 128 + i * 32 + r31) * 32;
#pragma unroll
    for (int j = 0; j < 2; ++j) b_row[j] = (wu * 64 + j * 32 + r31) * 32;

    auto stage = [&](int buf, int k0) {
#pragma unroll
        for (int c = 0; c < 4; ++c) {      // A: 256 rows = 16 chunks of 16
            int r0 = wave * 16 + c * 64;
            const bf16_t* gp = Ag + (size_t)(r0 + ld_r) * D_DIM + k0 + ld_c;
            __builtin_amdgcn_global_load_lds(
                (const __attribute__((address_space(1))) unsigned int*)gp,
                (__attribute__((address_space(3))) unsigned int*)&As[buf][r0 * 32],
                16, 0, 0);
        }
#pragma unroll
        for (int c = 0; c < 2; ++c) {      // B: 128 rows
            int r0 = wave * 16 + c * 64;
            const bf16_t* gp = Bg + (size_t)(r0 + ld_r) * D_DIM + k0 + ld_c;
            __builtin_amdgcn_global_load_lds(
                (const __attribute__((address_space(1))) unsigned int*)gp,
                (__attribute__((address_space(3))) unsigned int*)&Bs[buf][r0 * 32],
                16, 0, 0);
        }
    };

    stage(0, 0);

    f32x16 acc[4][2] = {};

#pragma unroll 1
    for (int t = 0; t < 8; ++t) {
        __syncthreads();                       // publishes buffer t&1
        if (t < 7) stage((t + 1) & 1, (t + 1) * 32);

        const bf16_t* as = As[t & 1];
        const bf16_t* bs = Bs[t & 1];
#pragma unroll
        for (int s = 0; s < 2; ++s) {          // two K=16 steps per chunk
            const int ch = ((s << 1) | half) ^ pxor;   // swizzled 16B chunk
            bf16x8 av[4], bv[2];
#pragma unroll
            for (int i = 0; i < 4; ++i)
                av[i] = *(const bf16x8*)&as[a_row[i] + ch * 8];
#pragma unroll
            for (int j = 0; j < 2; ++j)
                bv[j] = *(const bf16x8*)&bs[b_row[j] + ch * 8];
#pragma unroll
            for (int i = 0; i < 4; ++i)
#pragma unroll
                for (int j = 0; j < 2; ++j)
                    acc[i][j] = __builtin_amdgcn_mfma_f32_32x32x16_bf16(
                        av[i], bv[j], acc[i][j], 0, 0, 0);
        }
    }

    // Epilogue (uniform, diag handled by diag_kernel):
    // local += log2( prod_8 (1 + 2^(v + b2)) ) per 8-element group.
    const float b2 = bias[0] * LOG2E;
    float local = 0.0f;
#pragma unroll
    for (int i = 0; i < 4; ++i)
#pragma unroll
        for (int j = 0; j < 2; ++j)
#pragma unroll
            for (int g = 0; g < 2; ++g) {
                float x[8];
#pragma unroll
                for (int e = 0; e < 8; ++e)
                    x[e] = exp2_fast(acc[i][j][g * 8 + e] + b2);
                float p = 1.0f + x[0];
#pragma unroll
                for (int e = 1; e < 8; ++e)
                    p = fmaf(p, x[e], p);      // p *= (1 + x[e])
                local += log2_fast(p);
            }

#pragma unroll
    for (int off = 32; off > 0; off >>= 1)
        local += __shfl_xor(local, off, 64);
    if (lane == 0) red[wave] = local;
    __syncthreads();
    if (tid == 0) {
        float total = (red[0] + red[1]) + (red[2] + red[3]);
        atomicAdd(out, total * (LN2 / (float)N));
    }
}

extern "C" void kernel_launch(void* const* d_in, const int* in_sizes, int n_in,
                              void* d_out, int out_size, void* d_ws, size_t ws_size,
                              hipStream_t stream) {
    const float* img = (const float*)d_in[0];
    const float* txt = (const float*)d_in[1];
    const float* tp  = (const float*)d_in[2];
    const float* bs  = (const float*)d_in[3];
    float* out = (float*)d_out;
    int N = in_sizes[0] / D_DIM;    // 16384

    bf16_t* Ab = (bf16_t*)d_ws;                 // 8 MB
    bf16_t* Bb = Ab + (size_t)N * D_DIM;        // +8 MB

    norm_cast_kernel<<<(2 * N) / 4, 256, 0, stream>>>(img, txt, tp, Ab, Bb, out, N);
    diag_kernel<<<128, 256, 0, stream>>>(Ab, Bb, bs, out, N);

    dim3 grid(N / 128, N / 256);    // 128 x 64 = 8192 blocks
    siglip_loss_kernel<<<grid, 256, 0, stream>>>(Ab, Bb, bs, out, N);
}

// Round 7
// 259.748 us; speedup vs baseline: 2.0893x; 1.0176x over previous
//
#include <hip/hip_runtime.h>

typedef __bf16 bf16_t;
typedef __bf16 bf16x4 __attribute__((ext_vector_type(4)));
typedef __bf16 bf16x8 __attribute__((ext_vector_type(8)));
typedef float f32x4 __attribute__((ext_vector_type(4)));

#define D_DIM 256
#define LOG2E 1.4426950408889634f
#define LN2   0.6931471805599453f

#if __has_builtin(__builtin_amdgcn_exp2f)
static __device__ __forceinline__ float exp2_fast(float x) { return __builtin_amdgcn_exp2f(x); }
#else
static __device__ __forceinline__ float exp2_fast(float x) { return __expf(x * LN2); }
#endif
#if __has_builtin(__builtin_amdgcn_logf)
static __device__ __forceinline__ float log2_fast(float x) { return __builtin_amdgcn_logf(x); }
#else
static __device__ __forceinline__ float log2_fast(float x) { return __logf(x) * LOG2E; }
#endif

// Kernel 1: L2-normalize rows fp32->bf16; img rows pre-scaled by exp(t')*log2e
// so the GEMM accumulator is directly z2 - b2 (log2 domain). Zeroes out[0]
// (stream-ordered before main kernel's atomics; diag +b2 terms handled inline).
__global__ __launch_bounds__(256) void norm_cast_kernel(
    const float* __restrict__ img, const float* __restrict__ txt,
    const float* __restrict__ t_prime,
    bf16_t* __restrict__ Ab, bf16_t* __restrict__ Bb,
    float* __restrict__ out, int N)
{
    int wave = threadIdx.x >> 6;
    int lane = threadIdx.x & 63;
    int row  = blockIdx.x * 4 + wave;

    const float* src;
    bf16_t* dst;
    float scale;
    if (row < N) {
        src = img + (size_t)row * D_DIM;
        dst = Ab  + (size_t)row * D_DIM;
        scale = __expf(t_prime[0]) * LOG2E;
    } else {
        src = txt + (size_t)(row - N) * D_DIM;
        dst = Bb  + (size_t)(row - N) * D_DIM;
        scale = 1.0f;
    }

    float4 v = ((const float4*)src)[lane];
    float ss = v.x * v.x + v.y * v.y + v.z * v.z + v.w * v.w;
#pragma unroll
    for (int off = 32; off > 0; off >>= 1)
        ss += __shfl_xor(ss, off, 64);

    float inv = scale / fmaxf(sqrtf(ss), 1e-12f);

    bf16x4 o;
    o[0] = (bf16_t)(v.x * inv);
    o[1] = (bf16_t)(v.y * inv);
    o[2] = (bf16_t)(v.z * inv);
    o[3] = (bf16_t)(v.w * inv);
    *(bf16x4*)(dst + lane * 4) = o;

    if (blockIdx.x == 0 && threadIdx.x == 0) out[0] = 0.0f;
}

// Kernel 2: main GEMM + softplus-sum + inline diagonal correction.
//  Block = 512 thr (8 waves), tile 256x256; wave tile 128x64 = 8x4 of
//  16x16x32 bf16 MFMA (acc = 32 x f32x4). K = 8 chunks of 32, double-buffered
//  LDS (A 2x16KB + B 2x16KB = 64 KB -> 2 blocks/CU, 4 waves/SIMD), ONE
//  barrier per chunk, prefetch issued right after each barrier.
//  LDS read geometry is the R4/R5-verified ZERO-conflict pattern:
//  row = m16 (lane&15), chunk = quad ^ ((m16>>1)&3), 64-B rows.
//  Diagonal blocks (bx==by, 64 of 4096) subtract z2 = acc+b2 inline.
__global__ __launch_bounds__(512, 2) void siglip_loss_kernel(
    const bf16_t* __restrict__ A, const bf16_t* __restrict__ B,
    const float* __restrict__ bias, float* __restrict__ out, int N)
{
    __shared__ bf16_t As[2][256 * 32];   // 2 x 16 KB
    __shared__ bf16_t Bs[2][256 * 32];   // 2 x 16 KB
    __shared__ float red[8];

    const int tid  = threadIdx.x;
    const int wave = tid >> 6;        // 0..7
    const int lane = tid & 63;
    const int m16  = lane & 15;
    const int quad = lane >> 4;       // 0..3
    const int wv   = wave >> 2;       // 0..1 : 128-row half
    const int wu   = wave & 3;        // 0..3 : 64-col quarter

    const int rowBase = blockIdx.y * 256;
    const int colBase = blockIdx.x * 256;

    const bf16_t* Ag = A + (size_t)rowBase * D_DIM;
    const bf16_t* Bg = B + (size_t)colBase * D_DIM;

    // staging lane map (R4-verified): row = l>>2, src chunk (l&3)^((row>>1)&3)
    const int ld_r = lane >> 2;
    const int ld_c = ((lane & 3) ^ ((ld_r >> 1) & 3)) * 8;

    // fragment read offsets (R4-verified zero-conflict geometry)
    const int swz = (quad ^ ((m16 >> 1) & 3)) * 8;
    int a_off[8], b_off[4];
#pragma unroll
    for (int i = 0; i < 8; ++i) a_off[i] = (wv * 128 + i * 16 + m16) * 32 + swz;
#pragma unroll
    for (int j = 0; j < 4; ++j) b_off[j] = (wu * 64 + j * 16 + m16) * 32 + swz;

    auto stage = [&](int buf, int k0) {
#pragma unroll
        for (int c = 0; c < 2; ++c) {
            int r0 = wave * 32 + c * 16;       // rows 0..255 over 8 waves
            const bf16_t* gpA = Ag + (size_t)(r0 + ld_r) * D_DIM + k0 + ld_c;
            const bf16_t* gpB = Bg + (size_t)(r0 + ld_r) * D_DIM + k0 + ld_c;
            __builtin_amdgcn_global_load_lds(
                (const __attribute__((address_space(1))) unsigned int*)gpA,
                (__attribute__((address_space(3))) unsigned int*)&As[buf][r0 * 32],
                16, 0, 0);
            __builtin_amdgcn_global_load_lds(
                (const __attribute__((address_space(1))) unsigned int*)gpB,
                (__attribute__((address_space(3))) unsigned int*)&Bs[buf][r0 * 32],
                16, 0, 0);
        }
    };

    stage(0, 0);

    f32x4 acc[8][4] = {};

#pragma unroll 1
    for (int t = 0; t < 8; ++t) {
        __syncthreads();                       // publishes buffer t&1
        if (t < 7) stage((t + 1) & 1, (t + 1) * 32);

        const bf16_t* as = As[t & 1];
        const bf16_t* bs = Bs[t & 1];
        bf16x8 av[8], bv[4];
#pragma unroll
        for (int i = 0; i < 8; ++i) av[i] = *(const bf16x8*)&as[a_off[i]];
#pragma unroll
        for (int j = 0; j < 4; ++j) bv[j] = *(const bf16x8*)&bs[b_off[j]];
#pragma unroll
        for (int i = 0; i < 8; ++i)
#pragma unroll
            for (int j = 0; j < 4; ++j)
                acc[i][j] = __builtin_amdgcn_mfma_f32_16x16x32_bf16(
                    av[i], bv[j], acc[i][j], 0, 0, 0);
    }

    // Epilogue: local += log2( prod_8 (1 + 2^(acc + b2)) ) per 8-elem group.
    const float b2 = bias[0] * LOG2E;
    float local = 0.0f;
#pragma unroll
    for (int i = 0; i < 8; ++i)
#pragma unroll
        for (int jp = 0; jp < 2; ++jp) {
            float x[8];
#pragma unroll
            for (int jj = 0; jj < 2; ++jj)
#pragma unroll
                for (int r = 0; r < 4; ++r)
                    x[jj * 4 + r] = exp2_fast(acc[i][jp * 2 + jj][r] + b2);
            float p = 1.0f + x[0];
#pragma unroll
            for (int e = 1; e < 8; ++e)
                p = fmaf(p, x[e], p);          // p *= (1 + x[e])
            local += log2_fast(p);
        }

    // Diagonal correction: only the 64 blocks with bx==by can hold diagonal
    // elements. softplus(-z) = softplus(z) - z -> subtract z2 = acc + b2.
    if (rowBase == colBase) {
#pragma unroll
        for (int i = 0; i < 8; ++i)
#pragma unroll
            for (int j = 0; j < 4; ++j)
#pragma unroll
                for (int r = 0; r < 4; ++r) {
                    // C/D layout (R1-verified): col = m16, row = quad*4 + r
                    int grow = wv * 128 + i * 16 + quad * 4 + r;
                    int gcol = wu * 64 + j * 16 + m16;
                    if (grow == gcol) local -= acc[i][j][r] + b2;
                }
    }

#pragma unroll
    for (int off = 32; off > 0; off >>= 1)
        local += __shfl_xor(local, off, 64);
    if (lane == 0) red[wave] = local;
    __syncthreads();
    if (tid == 0) {
        float total = 0.0f;
#pragma unroll
        for (int w = 0; w < 8; ++w) total += red[w];
        atomicAdd(out, total * (LN2 / (float)N));
    }
}

extern "C" void kernel_launch(void* const* d_in, const int* in_sizes, int n_in,
                              void* d_out, int out_size, void* d_ws, size_t ws_size,
                              hipStream_t stream) {
    const float* img = (const float*)d_in[0];
    const float* txt = (const float*)d_in[1];
    const float* tp  = (const float*)d_in[2];
    const float* bs  = (const float*)d_in[3];
    float* out = (float*)d_out;
    int N = in_sizes[0] / D_DIM;    // 16384

    bf16_t* Ab = (bf16_t*)d_ws;                 // 8 MB
    bf16_t* Bb = Ab + (size_t)N * D_DIM;        // +8 MB

    norm_cast_kernel<<<(2 * N) / 4, 256, 0, stream>>>(img, txt, tp, Ab, Bb, out, N);

    dim3 grid(N / 256, N / 256);    // 64 x 64 = 4096 blocks
    siglip_loss_kernel<<<grid, 512, 0, stream>>>(Ab, Bb, bs, out, N);
}